// Round 1
// baseline (666.730 us; speedup 1.0000x reference)
//
#include <hip/hip_runtime.h>
#include <hip/hip_bf16.h>

#define N_NODES 100000
#define N_EDGES 1600000
#define N_HOPS 3
#define D_FEAT 128
#define D_HID 256
#define N_GRAPHS 64
#define CHUNK 16

// workspace layout:
//   s     [64][256] f32 at offset 0      (65536 B)
//   t     [64]      f32 at offset 65536  (256 B)
//   coeff [N_NODES][64] f32 at offset 1MB (25.6 MB)
#define WS_T_OFF 65536
#define WS_COEFF_OFF (1u << 20)

__global__ void node_init_kernel(const int* __restrict__ batch,
                                 const float* __restrict__ prop_w,
                                 float* __restrict__ coeff) {
    int n = blockIdx.x * 256 + threadIdx.x;
    if (n < N_NODES) {
        coeff[(size_t)n * 64 + batch[n]] = prop_w[0];
    }
}

__global__ void edge_kernel(const int* __restrict__ ei,
                            const float* __restrict__ ew,
                            const int* __restrict__ batch,
                            const float* __restrict__ prop_w,
                            float* __restrict__ coeff) {
    int e = blockIdx.x * 256 + threadIdx.x;
    int hop = blockIdx.y;
    if (e < N_EDGES) {
        int src = ei[(size_t)(hop * 2) * N_EDGES + e];
        int dst = ei[(size_t)(hop * 2 + 1) * N_EDGES + e];
        float w = ew[(size_t)hop * N_EDGES + e];
        int g = batch[dst];
        atomicAdd(&coeff[(size_t)src * 64 + g], prop_w[hop + 1] * w);
    }
}

// Fused: S[64][256] += coeff_chunk^T @ relu(x_chunk @ W1 + b1); t[g] += sum coeff
__global__ __launch_bounds__(256) void fused_kernel(
    const float* __restrict__ x,
    const float* __restrict__ w1,
    const float* __restrict__ b1,
    const float* __restrict__ coeff,
    float* __restrict__ s,
    float* __restrict__ t) {
    __shared__ float x_lds[CHUNK][128];   // 8 KB
    __shared__ float ru[CHUNK][256];      // 16 KB
    __shared__ float c_lds[CHUNK][64];    // 4 KB

    const int tid = threadIdx.x;
    // u-stage mapping: thread handles n in {8*ng+a}, k in {kg, kg+128}
    const int ng = tid >> 7;    // 0..1
    const int kg = tid & 127;   // 0..127
    // s-stage mapping: thread handles g in {8*gq+i}, k in {kq+32*m}
    const int gq = tid >> 5;    // 0..7
    const int kq = tid & 31;    // 0..31

    const float b1v0 = b1[kg];
    const float b1v1 = b1[kg + 128];

    float sacc[8][8];
    float tacc[8];
#pragma unroll
    for (int i = 0; i < 8; i++) {
        tacc[i] = 0.f;
#pragma unroll
        for (int m = 0; m < 8; m++) sacc[i][m] = 0.f;
    }

    const int nchunks = (N_NODES + CHUNK - 1) / CHUNK;  // 6250 exactly
    for (int ci = blockIdx.x; ci < nchunks; ci += gridDim.x) {
        const int base = ci * CHUNK;

        // ---- stage x (16x128 floats = 512 float4) and coeff (16x64 = 256 float4)
        {
            const float4* xg = (const float4*)x;
#pragma unroll
            for (int r = 0; r < 2; r++) {
                int idx = tid + r * 256;     // 0..511
                int n = idx >> 5;
                int q = idx & 31;
                float4 v = make_float4(0.f, 0.f, 0.f, 0.f);
                if (base + n < N_NODES) v = xg[(size_t)(base + n) * 32 + q];
                *(float4*)&x_lds[n][q * 4] = v;
            }
            int n = tid >> 4;
            int q = tid & 15;
            float4 v = make_float4(0.f, 0.f, 0.f, 0.f);
            if (base + n < N_NODES)
                v = *(const float4*)&coeff[(size_t)(base + n) * 64 + q * 4];
            *(float4*)&c_lds[n][q * 4] = v;
        }
        __syncthreads();

        // ---- u-stage: ru = relu(x_chunk @ W1 + b1)
        {
            float acc[8][2];
#pragma unroll
            for (int a = 0; a < 8; a++) { acc[a][0] = b1v0; acc[a][1] = b1v1; }

            for (int j4 = 0; j4 < 32; j4++) {
                float4 xq[8];
#pragma unroll
                for (int a = 0; a < 8; a++)
                    xq[a] = *(const float4*)&x_lds[8 * ng + a][j4 * 4];
                float wv[4][2];
#pragma unroll
                for (int jj = 0; jj < 4; jj++) {
                    wv[jj][0] = w1[(size_t)(j4 * 4 + jj) * 256 + kg];
                    wv[jj][1] = w1[(size_t)(j4 * 4 + jj) * 256 + kg + 128];
                }
#pragma unroll
                for (int a = 0; a < 8; a++) {
                    acc[a][0] += xq[a].x * wv[0][0] + xq[a].y * wv[1][0]
                               + xq[a].z * wv[2][0] + xq[a].w * wv[3][0];
                    acc[a][1] += xq[a].x * wv[0][1] + xq[a].y * wv[1][1]
                               + xq[a].z * wv[2][1] + xq[a].w * wv[3][1];
                }
            }
#pragma unroll
            for (int a = 0; a < 8; a++) {
                ru[8 * ng + a][kg]       = fmaxf(acc[a][0], 0.f);
                ru[8 * ng + a][kg + 128] = fmaxf(acc[a][1], 0.f);
            }
        }
        __syncthreads();

        // ---- s-stage: sacc += c_chunk^T @ ru
        {
#pragma unroll 2
            for (int n = 0; n < CHUNK; n++) {
                float4 c0 = *(const float4*)&c_lds[n][8 * gq];
                float4 c1 = *(const float4*)&c_lds[n][8 * gq + 4];
                float cv[8] = {c0.x, c0.y, c0.z, c0.w, c1.x, c1.y, c1.z, c1.w};
                float rv[8];
#pragma unroll
                for (int m = 0; m < 8; m++) rv[m] = ru[n][kq + 32 * m];
#pragma unroll
                for (int i = 0; i < 8; i++) {
#pragma unroll
                    for (int m = 0; m < 8; m++) sacc[i][m] += cv[i] * rv[m];
                }
#pragma unroll
                for (int i = 0; i < 8; i++) tacc[i] += cv[i];
            }
        }
        __syncthreads();
    }

    // flush partials
#pragma unroll
    for (int i = 0; i < 8; i++) {
#pragma unroll
        for (int m = 0; m < 8; m++)
            atomicAdd(&s[(size_t)(8 * gq + i) * 256 + kq + 32 * m], sacc[i][m]);
    }
    if (kq == 0) {
#pragma unroll
        for (int i = 0; i < 8; i++) atomicAdd(&t[8 * gq + i], tacc[i]);
    }
}

__global__ void finalize_kernel(const float* __restrict__ s,
                                const float* __restrict__ t,
                                const float* __restrict__ w2,
                                const float* __restrict__ b2,
                                float* __restrict__ out) {
    __shared__ float red[128];
    const int g = blockIdx.x;
    const int f = threadIdx.x;  // 128 threads

    float acc = t[g] * b2[f];
    for (int k = 0; k < D_HID; k++)
        acc += s[(size_t)g * 256 + k] * w2[(size_t)k * 128 + f];

    // log_softmax over the 128 features
    red[f] = acc;
    __syncthreads();
    for (int off = 64; off > 0; off >>= 1) {
        if (f < off) red[f] = fmaxf(red[f], red[f + off]);
        __syncthreads();
    }
    float mx = red[0];
    __syncthreads();
    red[f] = expf(acc - mx);
    __syncthreads();
    for (int off = 64; off > 0; off >>= 1) {
        if (f < off) red[f] += red[f + off];
        __syncthreads();
    }
    float lse = logf(red[0]);
    out[(size_t)g * 128 + f] = acc - mx - lse;
}

extern "C" void kernel_launch(void* const* d_in, const int* in_sizes, int n_in,
                              void* d_out, int out_size, void* d_ws, size_t ws_size,
                              hipStream_t stream) {
    const float* x     = (const float*)d_in[0];
    const int*   ei    = (const int*)d_in[1];
    const float* ew    = (const float*)d_in[2];
    const int*   batch = (const int*)d_in[3];
    const float* w1    = (const float*)d_in[4];
    const float* b1    = (const float*)d_in[5];
    const float* w2    = (const float*)d_in[6];
    const float* b2    = (const float*)d_in[7];
    const float* pw    = (const float*)d_in[8];
    float* out = (float*)d_out;

    float* s     = (float*)d_ws;
    float* t     = (float*)((char*)d_ws + WS_T_OFF);
    float* coeff = (float*)((char*)d_ws + WS_COEFF_OFF);

    hipMemsetAsync(s, 0, 64 * 256 * sizeof(float) + 256, stream);
    hipMemsetAsync(coeff, 0, (size_t)N_NODES * 64 * sizeof(float), stream);

    node_init_kernel<<<dim3((N_NODES + 255) / 256), 256, 0, stream>>>(batch, pw, coeff);
    edge_kernel<<<dim3((N_EDGES + 255) / 256, N_HOPS), 256, 0, stream>>>(ei, ew, batch, pw, coeff);
    fused_kernel<<<dim3(512), 256, 0, stream>>>(x, w1, b1, coeff, s, t);
    finalize_kernel<<<dim3(64), 128, 0, stream>>>(s, t, w2, b2, out);
}

// Round 2
// 448.405 us; speedup vs baseline: 1.4869x; 1.4869x over previous
//
#include <hip/hip_runtime.h>
#include <hip/hip_bf16.h>

#define N_NODES 100000
#define N_EDGES 1600000
#define N_HOPS 3
#define D_FEAT 128
#define D_HID 256
#define N_GRAPHS 64

#define CHUNK 32
#define NCHUNK (N_NODES / CHUNK)   /* 3125 exact */
#define FG 512                     /* fused grid (2 blocks/CU) */

// ws layout (~40.1 MB total; assumes ws_size >= 42 MB):
//  [0, 25.6MB): coeff fp32 [N_NODES][64]   (phase 1)
//               then s_part bf16 [FG][64*256] = 16 MB (overlay; coeff dead by fused)
//  [26MB, 38.8MB): ct bf16, A-frag layout [NCHUNK][4][64][8]
//  [40MB): t fp32 [64]
//  [40MB+4KB): s_sum fp32 [64*256]
#define CT_OFF   (26u * 1024u * 1024u)
#define T_OFF    (40u * 1024u * 1024u)
#define SSUM_OFF (T_OFF + 4096u)

typedef __attribute__((ext_vector_type(4))) float f32x4;
typedef __attribute__((ext_vector_type(8))) short s16x8;

__device__ __forceinline__ unsigned short f2bf(float f) {
    union { float f; unsigned u; } v; v.f = f;
    return (unsigned short)(v.u >> 16);   // truncation: plenty of slack vs threshold
}
__device__ __forceinline__ float bf2f(unsigned short s) {
    union { float f; unsigned u; } v; v.u = ((unsigned)s) << 16;
    return v.f;
}
// pack two fp32 -> two bf16 (low short = lo) with one v_perm_b32
__device__ __forceinline__ unsigned pkbf(float lo, float hi) {
    union { float f; unsigned u; } a, b; a.f = hi; b.f = lo;
    return __builtin_amdgcn_perm(a.u, b.u, 0x07060302u);
}

__global__ void node_init_kernel(const int* __restrict__ batch,
                                 const float* __restrict__ prop_w,
                                 float* __restrict__ coeff) {
    int n = blockIdx.x * 256 + threadIdx.x;
    if (n < N_NODES) coeff[(size_t)n * 64 + batch[n]] = prop_w[0];
}

__global__ void edge_kernel(const int* __restrict__ ei,
                            const float* __restrict__ ew,
                            const int* __restrict__ batch,
                            const float* __restrict__ prop_w,
                            float* __restrict__ coeff) {
    int e = blockIdx.x * 256 + threadIdx.x;
    int hop = blockIdx.y;
    if (e < N_EDGES) {
        int src = ei[(size_t)(hop * 2) * N_EDGES + e];
        int dst = ei[(size_t)(hop * 2 + 1) * N_EDGES + e];
        float w = ew[(size_t)hop * N_EDGES + e];
        atomicAdd(&coeff[(size_t)src * 64 + batch[dst]], prop_w[hop + 1] * w);
    }
}

// coeff [node][g] fp32 -> ct bf16 in MFMA-A fragment layout:
// ct[((ci*4+gt)*64 + l)*8 + j] = coeff[ci*32 + 8*(l>>4)+j][16*gt + (l&15)]
__global__ __launch_bounds__(256) void ct_convert(const float* __restrict__ coeff,
                                                  unsigned short* __restrict__ ct) {
    int ci = blockIdx.x;
    int t = threadIdx.x;
    int gt = t >> 6, l = t & 63, q = l >> 4, c = l & 15;
    int base = ci * CHUNK;
    s16x8 v;
#pragma unroll
    for (int j = 0; j < 8; j++)
        v[j] = (short)f2bf(coeff[(size_t)(base + 8 * q + j) * 64 + 16 * gt + c]);
    *(s16x8*)&ct[(((size_t)ci * 4 + gt) * 64 + l) * 8] = v;
}

// t[g] = sum_n coeff[n][g]  (coalesced row reads, LDS reduce, 64 atomics/block)
__global__ __launch_bounds__(256) void t_kernel(const float* __restrict__ coeff,
                                                float* __restrict__ tg) {
    __shared__ float red[256][4];
    int t = threadIdx.x;
    int cg = t & 15, rep = t >> 4;
    int nbase = blockIdx.x * 256;
    float4 acc = make_float4(0.f, 0.f, 0.f, 0.f);
    for (int n = nbase + rep; n < nbase + 256 && n < N_NODES; n += 16) {
        float4 v = *(const float4*)&coeff[(size_t)n * 64 + cg * 4];
        acc.x += v.x; acc.y += v.y; acc.z += v.z; acc.w += v.w;
    }
    red[t][0] = acc.x; red[t][1] = acc.y; red[t][2] = acc.z; red[t][3] = acc.w;
    __syncthreads();
    if (t < 64) {
        int c2 = t >> 2, j = t & 3;
        float s = 0.f;
#pragma unroll
        for (int r = 0; r < 16; r++) s += red[r * 16 + c2][j];
        atomicAdd(&tg[t], s);
    }
}

// MFMA fused kernel: per chunk of 32 nodes,
//   U = relu(X@W1 + b1)  (stage 1, W1 frags in registers)
//   S += Ct^T @ U        (stage 2)
// Wave w owns hid columns [64w, 64w+64): writes AND reads only its own U_t rows
// -> no __syncthreads() anywhere in the loop.
__global__ __launch_bounds__(256, 2) void fused_kernel(
    const float* __restrict__ x,
    const float* __restrict__ w1,
    const float* __restrict__ b1,
    const unsigned short* __restrict__ ct,
    unsigned short* __restrict__ s_part) {

    __shared__ __align__(16) unsigned short Ut[256 * 40];  // [hid][node], 40-short stride

    const int tid = threadIdx.x;
    const int w = tid >> 6, l = tid & 63, q = l >> 4, c = l & 15;
    const int wcol = w * 64;

    // persistent W1 B-fragments: w1f[nt][ks][j] = w1[32ks+8q+j][wcol+16nt+c]
    s16x8 w1f[4][4];
#pragma unroll
    for (int nt = 0; nt < 4; nt++)
#pragma unroll
        for (int ks = 0; ks < 4; ks++) {
            s16x8 v;
#pragma unroll
            for (int j = 0; j < 8; j++)
                v[j] = (short)f2bf(w1[(size_t)(32 * ks + 8 * q + j) * 256 + wcol + 16 * nt + c]);
            w1f[nt][ks] = v;
        }

    float bias[4];
#pragma unroll
    for (int nt = 0; nt < 4; nt++) bias[nt] = b1[wcol + 16 * nt + c];

    f32x4 sacc[4][4];
#pragma unroll
    for (int gt = 0; gt < 4; gt++)
#pragma unroll
        for (int nt = 0; nt < 4; nt++) sacc[gt][nt] = (f32x4)0.f;

    for (int ci = blockIdx.x; ci < NCHUNK; ci += FG) {
        const int base = ci * CHUNK;

        // Ct A-fragments (independent of everything -> issue early)
        s16x8 ctf[4];
#pragma unroll
        for (int gt = 0; gt < 4; gt++)
            ctf[gt] = *(const s16x8*)&ct[(((size_t)ci * 4 + gt) * 64 + l) * 8];

        // X A-fragments: af[mt][ks][j] = bf16(x[base+16mt+c][32ks+8q+j])
        s16x8 af[2][4];
#pragma unroll
        for (int mt = 0; mt < 2; mt++)
#pragma unroll
            for (int ks = 0; ks < 4; ks++) {
                const float4* p = (const float4*)&x[(size_t)(base + 16 * mt + c) * 128 + 32 * ks + 8 * q];
                float4 a0 = p[0], a1 = p[1];
                union { s16x8 v; unsigned u[4]; } r;
                r.u[0] = pkbf(a0.x, a0.y);
                r.u[1] = pkbf(a0.z, a0.w);
                r.u[2] = pkbf(a1.x, a1.y);
                r.u[3] = pkbf(a1.z, a1.w);
                af[mt][ks] = r.v;
            }

        // stage 1: U tiles (C-layout: row=node=4q+reg, col=hid=c)
        f32x4 u[2][4];
#pragma unroll
        for (int mt = 0; mt < 2; mt++)
#pragma unroll
            for (int nt = 0; nt < 4; nt++) {
                f32x4 a; a[0] = a[1] = a[2] = a[3] = bias[nt];
                u[mt][nt] = a;
            }
#pragma unroll
        for (int ks = 0; ks < 4; ks++)
#pragma unroll
            for (int mt = 0; mt < 2; mt++)
#pragma unroll
                for (int nt = 0; nt < 4; nt++)
                    u[mt][nt] = __builtin_amdgcn_mfma_f32_16x16x32_bf16(
                        af[mt][ks], w1f[nt][ks], u[mt][nt], 0, 0, 0);

        // relu + pack to bf16, transpose through LDS (own rows only)
#pragma unroll
        for (int mt = 0; mt < 2; mt++)
#pragma unroll
            for (int nt = 0; nt < 4; nt++) {
                f32x4 v = u[mt][nt];
                uint2 d;
                d.x = pkbf(fmaxf(v[0], 0.f), fmaxf(v[1], 0.f));
                d.y = pkbf(fmaxf(v[2], 0.f), fmaxf(v[3], 0.f));
                int hid = wcol + 16 * nt + c;
                *(uint2*)&Ut[hid * 40 + 16 * mt + 4 * q] = d;
            }

        // stage 2: B-frag uf[j] = U[node=8q+j][hid]; same-wave LDS, DS pipe is in-order
#pragma unroll
        for (int nt = 0; nt < 4; nt++) {
            int hid = wcol + 16 * nt + c;
            s16x8 uf = *(const s16x8*)&Ut[hid * 40 + 8 * q];
#pragma unroll
            for (int gt = 0; gt < 4; gt++)
                sacc[gt][nt] = __builtin_amdgcn_mfma_f32_16x16x32_bf16(
                    ctf[gt], uf, sacc[gt][nt], 0, 0, 0);
        }
    }

    // per-block bf16 partials (no atomics): D row = g = 16gt+4q+reg, col = hid
    unsigned short* my = s_part + (size_t)blockIdx.x * (64 * 256);
#pragma unroll
    for (int gt = 0; gt < 4; gt++)
#pragma unroll
        for (int nt = 0; nt < 4; nt++)
#pragma unroll
            for (int r = 0; r < 4; r++) {
                int g = 16 * gt + 4 * q + r;
                int hid = wcol + 16 * nt + c;
                my[g * 256 + hid] = f2bf(sacc[gt][nt][r]);
            }
}

__global__ __launch_bounds__(256) void reduce_kernel(const unsigned short* __restrict__ s_part,
                                                     float* __restrict__ s_sum) {
    int e = blockIdx.x * 256 + threadIdx.x;   // 64 blocks x 256 = 16384
    float a0 = 0.f, a1 = 0.f, a2 = 0.f, a3 = 0.f;
    for (int b = 0; b < FG; b += 4) {
        a0 += bf2f(s_part[(size_t)(b + 0) * 16384 + e]);
        a1 += bf2f(s_part[(size_t)(b + 1) * 16384 + e]);
        a2 += bf2f(s_part[(size_t)(b + 2) * 16384 + e]);
        a3 += bf2f(s_part[(size_t)(b + 3) * 16384 + e]);
    }
    s_sum[e] = (a0 + a1) + (a2 + a3);
}

__global__ void finalize_kernel(const float* __restrict__ s,
                                const float* __restrict__ t,
                                const float* __restrict__ w2,
                                const float* __restrict__ b2,
                                float* __restrict__ out) {
    __shared__ float red[128];
    const int g = blockIdx.x;
    const int f = threadIdx.x;  // 128 threads

    float acc = t[g] * b2[f];
    for (int k = 0; k < D_HID; k++)
        acc += s[(size_t)g * 256 + k] * w2[(size_t)k * 128 + f];

    red[f] = acc;
    __syncthreads();
    for (int off = 64; off > 0; off >>= 1) {
        if (f < off) red[f] = fmaxf(red[f], red[f + off]);
        __syncthreads();
    }
    float mx = red[0];
    __syncthreads();
    red[f] = expf(acc - mx);
    __syncthreads();
    for (int off = 64; off > 0; off >>= 1) {
        if (f < off) red[f] += red[f + off];
        __syncthreads();
    }
    float lse = logf(red[0]);
    out[(size_t)g * 128 + f] = acc - mx - lse;
}

extern "C" void kernel_launch(void* const* d_in, const int* in_sizes, int n_in,
                              void* d_out, int out_size, void* d_ws, size_t ws_size,
                              hipStream_t stream) {
    const float* x     = (const float*)d_in[0];
    const int*   ei    = (const int*)d_in[1];
    const float* ew    = (const float*)d_in[2];
    const int*   batch = (const int*)d_in[3];
    const float* w1    = (const float*)d_in[4];
    const float* b1    = (const float*)d_in[5];
    const float* w2    = (const float*)d_in[6];
    const float* b2    = (const float*)d_in[7];
    const float* pw    = (const float*)d_in[8];
    float* out = (float*)d_out;

    float*          coeff  = (float*)d_ws;
    unsigned short* s_part = (unsigned short*)d_ws;  // overlay: coeff dead once fused runs
    unsigned short* ct     = (unsigned short*)((char*)d_ws + CT_OFF);
    float*          tg     = (float*)((char*)d_ws + T_OFF);
    float*          s_sum  = (float*)((char*)d_ws + SSUM_OFF);

    hipMemsetAsync(coeff, 0, (size_t)N_NODES * 64 * sizeof(float), stream);
    hipMemsetAsync(tg, 0, 64 * sizeof(float), stream);

    node_init_kernel<<<dim3(391), 256, 0, stream>>>(batch, pw, coeff);
    edge_kernel<<<dim3(N_EDGES / 256, N_HOPS), 256, 0, stream>>>(ei, ew, batch, pw, coeff);
    ct_convert<<<dim3(NCHUNK), 256, 0, stream>>>(coeff, ct);
    t_kernel<<<dim3(391), 256, 0, stream>>>(coeff, tg);
    fused_kernel<<<dim3(FG), 256, 0, stream>>>(x, w1, b1, ct, s_part);
    reduce_kernel<<<dim3(64), 256, 0, stream>>>(s_part, s_sum);
    finalize_kernel<<<dim3(64), 128, 0, stream>>>(s_sum, tg, w2, b2, out);
}

// Round 3
// 270.134 us; speedup vs baseline: 2.4681x; 1.6599x over previous
//
#include <hip/hip_runtime.h>
#include <hip/hip_bf16.h>

#define N_NODES 100000
#define N_EDGES 1600000
#define N_HOPS 3
#define D_HID 256
#define N_GRAPHS 64

#define CHUNK 32
#define NCHUNK 3125          /* 100000/32 */
#define FG 512               /* fused grid */

#define NB 625               /* node buckets */
#define RB 160               /* nodes per bucket (5 chunks) */
#define NSH 4                /* cursor shadows */
#define CAP 2400             /* record capacity per (shadow,bucket); mean 1920 */
#define EPT 32               /* edges per thread in scatter */
#define EPB (256 * EPT)      /* 8192 edges per block */

// ws layout (total ~36.9 MB):
//  [0, 12.8MB)        ct bf16 A-frag [NCHUNK][4][64][8]
//  [12.8MB, 36.8MB)   records u32 [NSH][NB][CAP]   (phase A/B)
//    overlay: s_part bf16 [FG][64*256] = 16.8MB    (fused onward)
//  [36.8MB, ...)      cursors u32[NSH*NB] | tg f32[64] | s_sum f32[16384]
#define CT_OFF    0u
#define REC_OFF   12800000u
#define SPART_OFF REC_OFF
#define SMALL_OFF 36800000u
#define CUR_OFF   SMALL_OFF
#define TG_OFF    (SMALL_OFF + 16384u)
#define SSUM_OFF  (SMALL_OFF + 32768u)

typedef __attribute__((ext_vector_type(4))) float f32x4;
typedef __attribute__((ext_vector_type(8))) short s16x8;

__device__ __forceinline__ unsigned short f2bf_rne(float f) {
    union { float f; unsigned u; } v; v.f = f;
    unsigned r = v.u + 0x7FFFu + ((v.u >> 16) & 1u);
    return (unsigned short)(r >> 16);
}
__device__ __forceinline__ float bf2f(unsigned short s) {
    union { float f; unsigned u; } v; v.u = ((unsigned)s) << 16;
    return v.f;
}
__device__ __forceinline__ unsigned pk_rne(float lo, float hi) {
    return ((unsigned)f2bf_rne(hi) << 16) | (unsigned)f2bf_rne(lo);
}

// ---- Phase A: bin edges into per-(shadow,bucket) record ranges. No device
// atomics per edge: LDS-aggregated counts, one cursor reservation per
// (block,bucket), then plain stores into reserved contiguous slots.
__global__ __launch_bounds__(256) void scatter_kernel(
    const int* __restrict__ ei, const float* __restrict__ ew,
    const int* __restrict__ batch, const float* __restrict__ pw,
    unsigned* __restrict__ cursors, unsigned* __restrict__ records) {
    __shared__ unsigned cnt[NB], offs[NB], basearr[NB];
    const int tid = threadIdx.x;
    const int hop = blockIdx.y;
    const int ebase = blockIdx.x * EPB;
    const int sh = blockIdx.x & (NSH - 1);

    for (int i = tid; i < NB; i += 256) { cnt[i] = 0u; offs[i] = 0u; }
    __syncthreads();

    const float pwh = pw[hop + 1];
    const int* srcp = ei + (size_t)hop * 2 * N_EDGES;
    const int* dstp = srcp + N_EDGES;
    const float* ewp = ew + (size_t)hop * N_EDGES;

    unsigned rec[EPT], bkt[EPT];
#pragma unroll
    for (int k = 0; k < EPT; k++) {
        int e = ebase + tid + k * 256;
        if (e < N_EDGES) {
            int src = srcp[e];
            int dst = dstp[e];
            float v = pwh * ewp[e];
            int b = src / RB;
            bkt[k] = (unsigned)b;
            rec[k] = ((unsigned)f2bf_rne(v) << 16) |
                     (unsigned)((src - b * RB) * 64 + batch[dst]);
            atomicAdd(&cnt[b], 1u);
        } else {
            bkt[k] = 0xFFFFFFFFu;
        }
    }
    __syncthreads();
    for (int i = tid; i < NB; i += 256)
        if (cnt[i]) basearr[i] = atomicAdd(&cursors[sh * NB + i], cnt[i]);
    __syncthreads();
#pragma unroll
    for (int k = 0; k < EPT; k++) {
        if (bkt[k] != 0xFFFFFFFFu) {
            unsigned o = atomicAdd(&offs[bkt[k]], 1u);
            records[((size_t)sh * NB + bkt[k]) * CAP + basearr[bkt[k]] + o] = rec[k];
        }
    }
}

// ---- Phase B: one block per bucket. LDS f32 tile [160][65] (pad breaks bank
// aliasing; slot = m + (m>>6)). Replays records with LDS atomics, adds pw0
// term, emits ct in MFMA-A bf16 layout + tg column sums. coeff never hits HBM.
__global__ __launch_bounds__(256) void phaseB_kernel(
    const int* __restrict__ batch, const float* __restrict__ pw,
    const unsigned* __restrict__ cursors, const unsigned* __restrict__ records,
    unsigned short* __restrict__ ct, float* __restrict__ tg) {
    __shared__ float tile[RB * 65];
    const int tid = threadIdx.x;
    const int b = blockIdx.x;

    for (int i = tid; i < RB * 65; i += 256) tile[i] = 0.f;
    __syncthreads();

    if (tid < RB) atomicAdd(&tile[tid * 65 + batch[b * RB + tid]], pw[0]);

    for (int sh = 0; sh < NSH; sh++) {
        unsigned n = cursors[sh * NB + b];
        const unsigned* rp = records + ((size_t)sh * NB + b) * CAP;
        for (unsigned i = tid; i < n; i += 256) {
            unsigned r = rp[i];
            unsigned m = r & 0x3FFFu;
            atomicAdd(&tile[m + (m >> 6)], bf2f((unsigned short)(r >> 16)));
        }
    }
    __syncthreads();

    const int gt = tid >> 6, l = tid & 63, q = l >> 4, c = l & 15;
    for (int cc = 0; cc < 5; cc++) {
        s16x8 v;
#pragma unroll
        for (int j = 0; j < 8; j++)
            v[j] = (short)f2bf_rne(tile[(cc * 32 + 8 * q + j) * 65 + 16 * gt + c]);
        *(s16x8*)&ct[(((size_t)(b * 5 + cc) * 4 + gt) * 64 + l) * 8] = v;
    }
    if (tid < 64) {
        float sum = 0.f;
        for (int s = 0; s < RB; s++) sum += tile[s * 65 + tid];
        atomicAdd(&tg[tid], sum);
    }
}

// ---- Fused MFMA kernel: per 32-node chunk,
//   U = relu(X@W1 + b1)   (W1 B-frags persistent in registers)
//   S += Ct^T @ U
// x/ct staged once per block via LDS (register-prefetched); Ut transpose is
// wave-private (each wave owns hid cols [64w,64w+64)) -> 2 barriers/chunk.
__global__ __launch_bounds__(256, 2) void fused_kernel(
    const float* __restrict__ x,
    const float* __restrict__ w1,
    const float* __restrict__ b1,
    const unsigned short* __restrict__ ct,
    unsigned short* __restrict__ s_part) {

    __shared__ __align__(16) unsigned short Ut[256 * 40];     // 20 KB
    __shared__ __align__(16) unsigned short x_lds[32 * 136];  // 8.7 KB (pad 128->136)
    __shared__ __align__(16) unsigned short ct_lds[2048];     // 4 KB

    const int tid = threadIdx.x;
    const int w = tid >> 6, l = tid & 63, q = l >> 4, c = l & 15;
    const int wcol = w * 64;
    const int sr = tid >> 3, sk = (tid & 7) * 16;  // staging row / col

    // persistent W1 B-fragments: w1f[nt][ks][j] = w1[32ks+8q+j][wcol+16nt+c]
    s16x8 w1f[4][4];
#pragma unroll
    for (int nt = 0; nt < 4; nt++)
#pragma unroll
        for (int ks = 0; ks < 4; ks++) {
            s16x8 v;
#pragma unroll
            for (int j = 0; j < 8; j++)
                v[j] = (short)f2bf_rne(w1[(size_t)(32 * ks + 8 * q + j) * 256 + wcol + 16 * nt + c]);
            w1f[nt][ks] = v;
        }

    float bias[4];
#pragma unroll
    for (int nt = 0; nt < 4; nt++) bias[nt] = b1[wcol + 16 * nt + c];

    f32x4 sacc[4][4];
#pragma unroll
    for (int gt = 0; gt < 4; gt++)
#pragma unroll
        for (int nt = 0; nt < 4; nt++) sacc[gt][nt] = (f32x4)0.f;

    uint4 xp0, xp1;
    s16x8 ctp;

#define PREF(CI)                                                              \
    {                                                                         \
        const float4* p = (const float4*)&x[(size_t)((CI) * 32 + sr) * 128 + sk]; \
        float4 v0 = p[0], v1 = p[1], v2 = p[2], v3 = p[3];                    \
        xp0.x = pk_rne(v0.x, v0.y); xp0.y = pk_rne(v0.z, v0.w);               \
        xp0.z = pk_rne(v1.x, v1.y); xp0.w = pk_rne(v1.z, v1.w);               \
        xp1.x = pk_rne(v2.x, v2.y); xp1.y = pk_rne(v2.z, v2.w);               \
        xp1.z = pk_rne(v3.x, v3.y); xp1.w = pk_rne(v3.z, v3.w);               \
        ctp = *(const s16x8*)&ct[(size_t)(CI) * 2048 + tid * 8];              \
    }

    int ci = blockIdx.x;
    if (ci < NCHUNK) PREF(ci);

    for (; ci < NCHUNK; ci += FG) {
        // commit staged data to LDS
        *(uint4*)&x_lds[sr * 136 + sk] = xp0;
        *(uint4*)&x_lds[sr * 136 + sk + 8] = xp1;
        *(s16x8*)&ct_lds[tid * 8] = ctp;
        __syncthreads();

        s16x8 af[2][4], ctf[4];
#pragma unroll
        for (int mt = 0; mt < 2; mt++)
#pragma unroll
            for (int ks = 0; ks < 4; ks++)
                af[mt][ks] = *(const s16x8*)&x_lds[(16 * mt + c) * 136 + 32 * ks + 8 * q];
#pragma unroll
        for (int gt = 0; gt < 4; gt++)
            ctf[gt] = *(const s16x8*)&ct_lds[(gt * 64 + l) * 8];
        __syncthreads();

        if (ci + FG < NCHUNK) PREF(ci + FG);  // global loads fly during compute

        // stage 1: U = relu(X@W1 + b1)  (C-layout: node = 16mt+4q+reg, hid col = c)
        f32x4 u[2][4];
#pragma unroll
        for (int mt = 0; mt < 2; mt++)
#pragma unroll
            for (int nt = 0; nt < 4; nt++) {
                f32x4 a; a[0] = a[1] = a[2] = a[3] = bias[nt];
                u[mt][nt] = a;
            }
#pragma unroll
        for (int ks = 0; ks < 4; ks++)
#pragma unroll
            for (int mt = 0; mt < 2; mt++)
#pragma unroll
                for (int nt = 0; nt < 4; nt++)
                    u[mt][nt] = __builtin_amdgcn_mfma_f32_16x16x32_bf16(
                        af[mt][ks], w1f[nt][ks], u[mt][nt], 0, 0, 0);

        // relu + RNE pack, transpose through wave-private Ut rows
#pragma unroll
        for (int mt = 0; mt < 2; mt++)
#pragma unroll
            for (int nt = 0; nt < 4; nt++) {
                f32x4 v = u[mt][nt];
                uint2 d;
                d.x = pk_rne(fmaxf(v[0], 0.f), fmaxf(v[1], 0.f));
                d.y = pk_rne(fmaxf(v[2], 0.f), fmaxf(v[3], 0.f));
                *(uint2*)&Ut[(wcol + 16 * nt + c) * 40 + 16 * mt + 4 * q] = d;
            }

        // stage 2: S += Ct^T @ U (B-frag from own Ut rows; same-wave DS ordering)
#pragma unroll
        for (int nt = 0; nt < 4; nt++) {
            s16x8 uf = *(const s16x8*)&Ut[(wcol + 16 * nt + c) * 40 + 8 * q];
#pragma unroll
            for (int gt = 0; gt < 4; gt++)
                sacc[gt][nt] = __builtin_amdgcn_mfma_f32_16x16x32_bf16(
                    ctf[gt], uf, sacc[gt][nt], 0, 0, 0);
        }
    }
#undef PREF

    // per-block bf16 partials (D row = g = 16gt+4q+reg, col = hid)
    unsigned short* my = s_part + (size_t)blockIdx.x * (64 * 256);
#pragma unroll
    for (int gt = 0; gt < 4; gt++)
#pragma unroll
        for (int nt = 0; nt < 4; nt++)
#pragma unroll
            for (int r = 0; r < 4; r++)
                my[(16 * gt + 4 * q + r) * 256 + wcol + 16 * nt + c] =
                    f2bf_rne(sacc[gt][nt][r]);
}

__global__ __launch_bounds__(256) void reduce_kernel(const unsigned short* __restrict__ s_part,
                                                     float* __restrict__ s_sum) {
    int e = blockIdx.x * 256 + threadIdx.x;  // 64 x 256 = 16384
    float a0 = 0.f, a1 = 0.f, a2 = 0.f, a3 = 0.f;
    for (int b = 0; b < FG; b += 4) {
        a0 += bf2f(s_part[(size_t)(b + 0) * 16384 + e]);
        a1 += bf2f(s_part[(size_t)(b + 1) * 16384 + e]);
        a2 += bf2f(s_part[(size_t)(b + 2) * 16384 + e]);
        a3 += bf2f(s_part[(size_t)(b + 3) * 16384 + e]);
    }
    s_sum[e] = (a0 + a1) + (a2 + a3);
}

__global__ void finalize_kernel(const float* __restrict__ s,
                                const float* __restrict__ t,
                                const float* __restrict__ w2,
                                const float* __restrict__ b2,
                                float* __restrict__ out) {
    __shared__ float red[128];
    const int g = blockIdx.x;
    const int f = threadIdx.x;

    float acc = t[g] * b2[f];
    for (int k = 0; k < D_HID; k++)
        acc += s[(size_t)g * 256 + k] * w2[(size_t)k * 128 + f];

    red[f] = acc;
    __syncthreads();
    for (int off = 64; off > 0; off >>= 1) {
        if (f < off) red[f] = fmaxf(red[f], red[f + off]);
        __syncthreads();
    }
    float mx = red[0];
    __syncthreads();
    red[f] = expf(acc - mx);
    __syncthreads();
    for (int off = 64; off > 0; off >>= 1) {
        if (f < off) red[f] += red[f + off];
        __syncthreads();
    }
    float lse = logf(red[0]);
    out[(size_t)g * 128 + f] = acc - mx - lse;
}

extern "C" void kernel_launch(void* const* d_in, const int* in_sizes, int n_in,
                              void* d_out, int out_size, void* d_ws, size_t ws_size,
                              hipStream_t stream) {
    const float* x     = (const float*)d_in[0];
    const int*   ei    = (const int*)d_in[1];
    const float* ew    = (const float*)d_in[2];
    const int*   batch = (const int*)d_in[3];
    const float* w1    = (const float*)d_in[4];
    const float* b1    = (const float*)d_in[5];
    const float* w2    = (const float*)d_in[6];
    const float* b2    = (const float*)d_in[7];
    const float* pw    = (const float*)d_in[8];
    float* out = (float*)d_out;

    unsigned short* ctp     = (unsigned short*)((char*)d_ws + CT_OFF);
    unsigned*       records = (unsigned*)((char*)d_ws + REC_OFF);
    unsigned short* s_part  = (unsigned short*)((char*)d_ws + SPART_OFF);
    unsigned*       cursors = (unsigned*)((char*)d_ws + CUR_OFF);
    float*          tgp     = (float*)((char*)d_ws + TG_OFF);
    float*          s_sum   = (float*)((char*)d_ws + SSUM_OFF);

    hipMemsetAsync(cursors, 0, NSH * NB * sizeof(unsigned), stream);
    hipMemsetAsync(tgp, 0, 64 * sizeof(float), stream);

    scatter_kernel<<<dim3((N_EDGES + EPB - 1) / EPB, N_HOPS), 256, 0, stream>>>(
        ei, ew, batch, pw, cursors, records);
    phaseB_kernel<<<dim3(NB), 256, 0, stream>>>(batch, pw, cursors, records, ctp, tgp);
    fused_kernel<<<dim3(FG), 256, 0, stream>>>(x, w1, b1, ctp, s_part);
    reduce_kernel<<<dim3(64), 256, 0, stream>>>(s_part, s_sum);
    finalize_kernel<<<dim3(64), 128, 0, stream>>>(s_sum, tgp, w2, b2, out);
}